// Round 1
// baseline (17058.165 us; speedup 1.0000x reference)
//
#include <hip/hip_runtime.h>

// Persistent batched-GRU kernel for MI355X (gfx950).
// B=16384, T=1024, H=256. Each block owns 64 batch rows for all 1024 steps.
// gh = h @ W_hh^T via mfma_f32_16x16x32_bf16; gates/h/output in fp32.
// Wave w owns gate-matched column slice {w*32..+32} + 256/512 offsets so
// r,z,n align in its own accumulators (no cross-wave exchange for gating).

#define B_TOTAL 16384
#define T_LEN   1024
#define HID     256
#define M_ROWS  64                      // batch rows per block
#define NBLOCKS (B_TOTAL / M_ROWS)      // 256 -> 1 block/CU
#define NTHREADS 512                    // 8 waves
#define LDSW    264                     // h row stride in bf16 (pad 256+8: bank decorrelate)

typedef short  short8 __attribute__((ext_vector_type(8)));
typedef float  f32x4  __attribute__((ext_vector_type(4)));

__device__ __forceinline__ unsigned short f2b(float f) {
  // fp32 -> bf16 round-to-nearest-even
  unsigned u = __builtin_bit_cast(unsigned, f);
  u += 0x7fffu + ((u >> 16) & 1u);
  return (unsigned short)(u >> 16);
}

__device__ __forceinline__ float fast_sig(float x) {
  return 1.0f / (1.0f + __expf(-x));
}
__device__ __forceinline__ float fast_tanh(float x) {
  return 2.0f * fast_sig(2.0f * x) - 1.0f;   // tanh(x) = 2*sigmoid(2x) - 1
}

// Swizzle W_hh (768x256 f32 row-major) into fragment-major bf16 so a wave's
// B-frag load is one coalesced 1KB global_load_dwordx4:
// dst[((nt*8 + ks)*64 + lane)*8 + e] = bf16(W[nt*16 + (lane&15)][ks*32 + (lane>>4)*8 + e])
__global__ void prep_w(const float* __restrict__ w_hh, unsigned short* __restrict__ wsw) {
  int tid  = blockIdx.x * 256 + threadIdx.x;     // 196608 total
  int e    = tid & 7;
  int lane = (tid >> 3) & 63;
  int ks   = (tid >> 9) & 7;
  int nt   = tid >> 12;
  int row  = nt * 16 + (lane & 15);
  int col  = ks * 32 + (lane >> 4) * 8 + e;
  wsw[tid] = f2b(w_hh[row * 256 + col]);
}

__global__ __launch_bounds__(NTHREADS, 2) void gru_kernel(
    const float* __restrict__ x,
    const float* __restrict__ w_ih,
    const float* __restrict__ b_ih,
    const float* __restrict__ b_hh,
    const float* __restrict__ w_out,
    const float* __restrict__ b_out,
    const unsigned short* __restrict__ wsw,
    float* __restrict__ out)
{
  __shared__ unsigned short h_lds[M_ROWS * LDSW];   // bf16 h, A-operand source (~33 KB)
  __shared__ float out_part[8][M_ROWS];
  __shared__ float x_stage[M_ROWS];

  const int tid  = threadIdx.x;
  const int w    = tid >> 6;        // wave 0..7
  const int lane = tid & 63;
  const int r16  = lane & 15;       // col-within-tile (C layout) / row-within-tile (A/B layout)
  const int q    = lane >> 4;       // quad 0..3
  const long base = (long)blockIdx.x * M_ROWS;

  for (int i = tid; i < M_ROWS * LDSW; i += NTHREADS) h_lds[i] = 0;  // h0 = 0
  if (tid < M_ROWS) x_stage[tid] = x[(base + tid) * T_LEN + 0];

  // per-lane constants: this wave's columns c = g*256 + w*32 + j*16 + r16
  float wi_g[3][2], bt_r[2], bt_z[2], bih_n[2], bhh_n[2], wo[2];
#pragma unroll
  for (int j = 0; j < 2; ++j) {
    int c = w * 32 + j * 16 + r16;
    wi_g[0][j] = w_ih[c];
    wi_g[1][j] = w_ih[256 + c];
    wi_g[2][j] = w_ih[512 + c];
    bt_r[j]  = b_ih[c]       + b_hh[c];          // r,z: biases combine
    bt_z[j]  = b_ih[256 + c] + b_hh[256 + c];
    bih_n[j] = b_ih[512 + c];                    // n: r multiplies (gh_n + b_hh_n) only
    bhh_n[j] = b_hh[512 + c];
    wo[j]    = w_out[c];
  }
  const float bo = b_out[0];
  const f32x4 zero4 = {0.f, 0.f, 0.f, 0.f};

  f32x4 h_reg[4][2];                 // h in fp32, C-layout: row=mt*16+q*4+i, col=w*32+j*16+r16
#pragma unroll
  for (int mt = 0; mt < 4; ++mt)
#pragma unroll
    for (int j = 0; j < 2; ++j) h_reg[mt][j] = zero4;

  // B-frag base pointers: frag (g,j,ks) at ((g*16 + w*2 + j)*8 + ks)*64*8 + lane*8
  const unsigned short* bp[3][2];
#pragma unroll
  for (int g = 0; g < 3; ++g)
#pragma unroll
    for (int j = 0; j < 2; ++j)
      bp[g][j] = wsw + ((long)((g * 16 + w * 2 + j) * 8) * 64 + lane) * 8;

  __syncthreads();

  for (int t = 0; t < T_LEN; ++t) {
    // ---------- Phase A: gh = h @ W_hh^T  (this wave: 4 m-tiles x 6 n-tiles x 8 k-steps)
    f32x4 acc[4][3][2];
#pragma unroll
    for (int mt = 0; mt < 4; ++mt)
#pragma unroll
      for (int g = 0; g < 3; ++g)
#pragma unroll
        for (int j = 0; j < 2; ++j) acc[mt][g][j] = zero4;

#pragma unroll
    for (int ks = 0; ks < 8; ++ks) {
      short8 a[4];
#pragma unroll
      for (int mt = 0; mt < 4; ++mt) {
        // A layout: m = lane&15 (tile row), k = q*8 + e  -> 16B contiguous ds_read_b128
        const unsigned short* ap = &h_lds[(mt * 16 + r16) * LDSW + ks * 32 + q * 8];
        a[mt] = *(const short8*)ap;
      }
#pragma unroll
      for (int g = 0; g < 3; ++g)
#pragma unroll
        for (int j = 0; j < 2; ++j) {
          short8 b = *(const short8*)(bp[g][j] + ks * 64 * 8);
#pragma unroll
          for (int mt = 0; mt < 4; ++mt)
            acc[mt][g][j] = __builtin_amdgcn_mfma_f32_16x16x32_bf16(a[mt], b, acc[mt][g][j], 0, 0, 0);
        }
    }

    // ---------- Phase B: gates in-register (C layout: row=mt*16+q*4+i, col=w*32+j*16+r16)
    f32x4 vout[4];
#pragma unroll
    for (int mt = 0; mt < 4; ++mt) {
      f32x4 xv;
#pragma unroll
      for (int i = 0; i < 4; ++i) xv[i] = x_stage[mt * 16 + q * 4 + i];
      vout[mt] = zero4;
#pragma unroll
      for (int j = 0; j < 2; ++j) {
#pragma unroll
        for (int i = 0; i < 4; ++i) {
          float rg = fast_sig(acc[mt][0][j][i] + xv[i] * wi_g[0][j] + bt_r[j]);
          float zg = fast_sig(acc[mt][1][j][i] + xv[i] * wi_g[1][j] + bt_z[j]);
          float ng = fast_tanh(xv[i] * wi_g[2][j] + bih_n[j] + rg * (acc[mt][2][j][i] + bhh_n[j]));
          float hn = (1.0f - zg) * ng + zg * h_reg[mt][j][i];
          h_reg[mt][j][i] = hn;
          vout[mt][i] += fmaxf(hn, 0.0f) * wo[j];
        }
      }
      // reduce the 32-col partial over the 16 lanes of this quad-group
#pragma unroll
      for (int mask = 1; mask < 16; mask <<= 1)
#pragma unroll
        for (int i = 0; i < 4; ++i)
          vout[mt][i] += __shfl_xor(vout[mt][i], mask, 16);
    }

    __syncthreads();   // barrier1: all A-frag reads + x_stage reads of step t complete

    // ---------- Phase C: publish h_new (bf16) + out partials; stage x[t+1]
#pragma unroll
    for (int mt = 0; mt < 4; ++mt)
#pragma unroll
      for (int j = 0; j < 2; ++j)
#pragma unroll
        for (int i = 0; i < 4; ++i)
          h_lds[(mt * 16 + q * 4 + i) * LDSW + w * 32 + j * 16 + r16] = f2b(h_reg[mt][j][i]);
    if (r16 == 0) {
#pragma unroll
      for (int mt = 0; mt < 4; ++mt)
#pragma unroll
        for (int i = 0; i < 4; ++i)
          out_part[w][mt * 16 + q * 4 + i] = vout[mt][i];
    }
    if (tid < M_ROWS && t + 1 < T_LEN) x_stage[tid] = x[(base + tid) * T_LEN + t + 1];

    __syncthreads();   // barrier2: h_lds / out_part / x_stage ready

    // ---------- Phase D: final output for step t (out_part stable until next barrier1)
    if (tid < M_ROWS) {
      float o = bo;
#pragma unroll
      for (int ww = 0; ww < 8; ++ww) o += out_part[ww][tid];
      out[(base + tid) * T_LEN + t] = o;
    }
  }
}

extern "C" void kernel_launch(void* const* d_in, const int* in_sizes, int n_in,
                              void* d_out, int out_size, void* d_ws, size_t ws_size,
                              hipStream_t stream) {
  const float* x     = (const float*)d_in[0];
  const float* w_ih  = (const float*)d_in[1];
  const float* w_hh  = (const float*)d_in[2];
  const float* b_ih  = (const float*)d_in[3];
  const float* b_hh  = (const float*)d_in[4];
  const float* w_out = (const float*)d_in[5];
  const float* b_out = (const float*)d_in[6];
  unsigned short* wsw = (unsigned short*)d_ws;   // 768*256*2 = 384 KB of scratch
  float* out = (float*)d_out;

  prep_w<<<768, 256, 0, stream>>>(w_hh, wsw);
  gru_kernel<<<NBLOCKS, NTHREADS, 0, stream>>>(x, w_ih, b_ih, b_hh, w_out, b_out, wsw, out);
}